// Round 1
// baseline (322.686 us; speedup 1.0000x reference)
//
#include <hip/hip_runtime.h>

#define NNODES 50000
#define FEAT 256
#define NH 8
#define DHEAD 32
#define DEG 16
#define CDIM 256  // NH*DHEAD

#define BM 64
#define BN 64
#define BK 32

// Kernel 1: Wh[n][c] = sum_f h[n][f] * W[c/32][f][c%32] + bW[c]
// fp32 tiled GEMM, 256 threads, 16x16 thread grid, 4x4 microtile.
__global__ __launch_bounds__(256) void gemm_wh(
    const float* __restrict__ h, const float* __restrict__ W,
    const float* __restrict__ bW, float* __restrict__ Wh) {
  __shared__ float As[BK][BM + 4];
  __shared__ float Bs[BK][BN + 4];
  const int tid = threadIdx.x;
  const int row0 = blockIdx.x * BM;
  const int c0 = blockIdx.y * BN;
  const int tx = tid & 15, ty = tid >> 4;
  const int m0 = ty * 4, n0 = tx * 4;
  float acc[4][4] = {};
  const float4* h4 = (const float4*)h;
  const float4* W4 = (const float4*)W;
  for (int kt = 0; kt < FEAT / BK; ++kt) {
    // Load A tile: 64 rows x 32 k = 512 float4, 2 per thread.
#pragma unroll
    for (int p = 0; p < 2; ++p) {
      int fi = tid + p * 256;
      int r = fi >> 3, k4 = fi & 7;  // 8 float4 per row
      int grow = row0 + r;
      float4 v = make_float4(0.f, 0.f, 0.f, 0.f);
      if (grow < NNODES) v = h4[(size_t)grow * (FEAT / 4) + kt * 8 + k4];
      As[k4 * 4 + 0][r] = v.x;
      As[k4 * 4 + 1][r] = v.y;
      As[k4 * 4 + 2][r] = v.z;
      As[k4 * 4 + 3][r] = v.w;
    }
    // Load B tile: 32 k x 64 c = 512 float4. W layout [H][F][DH].
#pragma unroll
    for (int p = 0; p < 2; ++p) {
      int fi = tid + p * 256;
      int f = fi >> 4, c4 = fi & 15;  // 16 float4 per k-row
      int c = c0 + c4 * 4;            // 4-aligned -> never straddles head
      int hh = c >> 5, d = c & 31;
      int fg = kt * BK + f;
      float4 v = W4[hh * 2048 + fg * 8 + (d >> 2)];
      *(float4*)&Bs[f][c4 * 4] = v;
    }
    __syncthreads();
#pragma unroll
    for (int kk = 0; kk < BK; ++kk) {
      float4 a4 = *(const float4*)&As[kk][m0];
      float4 b4 = *(const float4*)&Bs[kk][n0];
      float a[4] = {a4.x, a4.y, a4.z, a4.w};
      float b[4] = {b4.x, b4.y, b4.z, b4.w};
#pragma unroll
      for (int i = 0; i < 4; ++i)
#pragma unroll
        for (int j = 0; j < 4; ++j) acc[i][j] += a[i] * b[j];
    }
    __syncthreads();
  }
  float4 bias = *(const float4*)&bW[c0 + n0];
  float4* Wh4 = (float4*)Wh;
#pragma unroll
  for (int i = 0; i < 4; ++i) {
    int grow = row0 + m0 + i;
    if (grow < NNODES) {
      float4 o;
      o.x = acc[i][0] + bias.x;
      o.y = acc[i][1] + bias.y;
      o.z = acc[i][2] + bias.z;
      o.w = acc[i][3] + bias.w;
      Wh4[(size_t)grow * (CDIM / 4) + (c0 + n0) / 4] = o;
    }
  }
}

// Kernel 1b: s12[n][0..7] = s1 (dot per head with a_src),
//            s12[n][8..15] = s2 + a_bias. One wave per node.
__global__ __launch_bounds__(256) void calc_s12(
    const float* __restrict__ Wh, const float* __restrict__ a_src,
    const float* __restrict__ a_dst, const float* __restrict__ a_bias,
    float* __restrict__ s12) {
  int lane = threadIdx.x & 63;
  int node = blockIdx.x * 4 + (threadIdx.x >> 6);
  const float4* Wh4 = (const float4*)Wh;
  const float4* as4 = (const float4*)a_src;
  const float4* ad4 = (const float4*)a_dst;
  float4 v = Wh4[(size_t)node * 64 + lane];
  float4 a1 = as4[lane];
  float4 a2 = ad4[lane];
  float acc1 = v.x * a1.x + v.y * a1.y + v.z * a1.z + v.w * a1.w;
  float acc2 = v.x * a2.x + v.y * a2.y + v.z * a2.z + v.w * a2.w;
  // reduce within 8-lane head groups (head = lane/8, DH=32 = 8 lanes * 4)
#pragma unroll
  for (int off = 1; off < 8; off <<= 1) {
    acc1 += __shfl_xor(acc1, off, 64);
    acc2 += __shfl_xor(acc2, off, 64);
  }
  if ((lane & 7) == 0) {
    int hh = lane >> 3;
    s12[(size_t)node * 16 + hh] = acc1;
    s12[(size_t)node * 16 + 8 + hh] = acc2 + a_bias[hh];
  }
}

// Kernel 2: per-node (wave-per-node) softmax over 16 contiguous incoming
// edges + weighted gather-sum of Wh[src] rows.
__global__ __launch_bounds__(256) void aggregate(
    const float* __restrict__ Wh, const float* __restrict__ s12,
    const int* __restrict__ src, float* __restrict__ out) {
  __shared__ int srcs_s[4][DEG];
  __shared__ float sc_s[4][DEG * NH];
  int wave = threadIdx.x >> 6, lane = threadIdx.x & 63;
  int n = blockIdx.x * 4 + wave;
  if (lane < DEG) srcs_s[wave][lane] = src[(size_t)n * DEG + lane];
  __syncthreads();
  int hh7 = lane & 7;
  float s2v = s12[(size_t)n * 16 + 8 + hh7];
  // 128 scores per node; each lane computes 2 (same head, edges e and e+8)
#pragma unroll
  for (int p = 0; p < 2; ++p) {
    int i = lane + p * 64;
    int e = i >> 3;
    int s = srcs_s[wave][e];
    float sc = s12[(size_t)s * 16 + hh7] + s2v;
    sc_s[wave][i] = sc > 0.f ? sc : 0.2f * sc;  // leaky relu
  }
  __syncthreads();
  if (lane < 8) {
    float m = -1e30f;
#pragma unroll
    for (int e = 0; e < DEG; ++e) m = fmaxf(m, sc_s[wave][e * 8 + lane]);
    float sum = 0.f;
#pragma unroll
    for (int e = 0; e < DEG; ++e) {
      float ex = __expf(sc_s[wave][e * 8 + lane] - m);
      sc_s[wave][e * 8 + lane] = ex;
      sum += ex;
    }
    float inv = 1.f / sum;
#pragma unroll
    for (int e = 0; e < DEG; ++e) sc_s[wave][e * 8 + lane] *= inv;
  }
  __syncthreads();
  int hh = lane >> 3;  // lane covers cols [lane*4, lane*4+4) -> head lane/8
  const float4* Wh4 = (const float4*)Wh;
  float4 acc = make_float4(0.f, 0.f, 0.f, 0.f);
#pragma unroll
  for (int e = 0; e < DEG; ++e) {
    float w = sc_s[wave][e * 8 + hh];
    float4 v = Wh4[(size_t)srcs_s[wave][e] * 64 + lane];
    acc.x += w * v.x;
    acc.y += w * v.y;
    acc.z += w * v.z;
    acc.w += w * v.w;
  }
  ((float4*)out)[(size_t)n * 64 + lane] = acc;
}

extern "C" void kernel_launch(void* const* d_in, const int* in_sizes, int n_in,
                              void* d_out, int out_size, void* d_ws, size_t ws_size,
                              hipStream_t stream) {
  const float* h = (const float*)d_in[0];
  const float* W = (const float*)d_in[1];
  const float* bW = (const float*)d_in[2];
  const float* a_src = (const float*)d_in[3];
  const float* a_dst = (const float*)d_in[4];
  const float* a_bias = (const float*)d_in[5];
  const int* src = (const int*)d_in[6];
  // d_in[7] (dst) unused: dst = repeat(arange(N), DEG) structurally, so
  // node n's incoming edges are exactly [n*DEG, (n+1)*DEG).
  float* out = (float*)d_out;

  float* Wh = (float*)d_ws;                       // [N][256] 51.2 MB
  float* s12 = Wh + (size_t)NNODES * CDIM;        // [N][16]   3.2 MB

  dim3 g1((NNODES + BM - 1) / BM, CDIM / BN);
  gemm_wh<<<g1, 256, 0, stream>>>(h, W, bW, Wh);
  calc_s12<<<NNODES / 4, 256, 0, stream>>>(Wh, a_src, a_dst, a_bias, s12);
  aggregate<<<NNODES / 4, 256, 0, stream>>>(Wh, s12, src, out);
}

// Round 2
// 217.059 us; speedup vs baseline: 1.4866x; 1.4866x over previous
//
#include <hip/hip_runtime.h>

#define NNODES 50000
#define FEAT 256
#define NH 8
#define DHEAD 32
#define DEG 16
#define CDIM 256  // NH*DHEAD

typedef __attribute__((ext_vector_type(4))) float floatx4;
typedef __attribute__((ext_vector_type(8))) short shortx8;

__device__ __forceinline__ unsigned short f2bf(float f) {
  union { float f; unsigned u; } v; v.f = f;
  unsigned r = v.u + 0x7fffu + ((v.u >> 16) & 1u);  // RN-even
  return (unsigned short)(r >> 16);
}
__device__ __forceinline__ float bf2f(unsigned short b) {
  union { unsigned u; float f; } v; v.u = ((unsigned)b) << 16;
  return v.f;
}

// Kernel 0: convert h (fp32) -> hb (bf16), and W [H][F][DH] fp32 ->
// Wt [c][k] bf16 (c = h*32+d). Blocks [0,12500) do h; [12500,12564) do W.
__global__ __launch_bounds__(256) void convert_inputs(
    const float* __restrict__ h, const float* __restrict__ W,
    unsigned short* __restrict__ hb, unsigned short* __restrict__ Wt) {
  int b = blockIdx.x;
  if (b < 12500) {
    int i4 = b * 256 + threadIdx.x;  // float4 index into h (3.2M total)
    float4 v = ((const float4*)h)[i4];
    ushort4 o;
    o.x = f2bf(v.x); o.y = f2bf(v.y); o.z = f2bf(v.z); o.w = f2bf(v.w);
    ((ushort4*)hb)[i4] = o;
  } else {
    int t = (b - 12500) * 256 + threadIdx.x;  // [0,16384), 4 elems each
#pragma unroll
    for (int j = 0; j < 4; ++j) {
      int idx = t * 4 + j;          // [0, 65536)
      int c = idx >> 8, k = idx & 255;
      Wt[idx] = f2bf(W[(size_t)(c >> 5) * (FEAT * DHEAD) + (size_t)k * DHEAD + (c & 31)]);
    }
  }
}

// Kernel 1: Whb[n][c] = bf16( sum_k hb[n][k] * Wt[c][k] + bW[c] )
// 128x128 tile, BK=32, 256 threads (4 waves, 2x2), 4x4 16x16x32 MFMA per wave.
__global__ __launch_bounds__(256) void gemm_mfma(
    const unsigned short* __restrict__ hb, const unsigned short* __restrict__ Wt,
    const float* __restrict__ bW, unsigned short* __restrict__ Whb) {
  __shared__ unsigned short As[128 * 32];
  __shared__ unsigned short Bs[128 * 32];
  const int w = threadIdx.x >> 6;     // wave 0..3
  const int lane = threadIdx.x & 63;
  const int wr = w >> 1, wc = w & 1;  // 2x2 wave grid
  const int row0 = blockIdx.x * 128;
  const int c0 = blockIdx.y * 128;
  const int lr = lane >> 2;           // 0..15 (row within 16-row chunk)
  const int lk = (lane & 3) * 8;      // k-offset 0/8/16/24
  const int mrow = lane & 15, quad = lane >> 4;

  floatx4 acc[4][4] = {};

  for (int kt = 0; kt < FEAT / 32; ++kt) {
    // Stage A: wave w covers rows [w*32, w*32+32), 2 issues of 16 rows
#pragma unroll
    for (int p = 0; p < 2; ++p) {
      int r = w * 32 + p * 16;
      int grow = row0 + r + lr;
      if (grow > NNODES - 1) grow = NNODES - 1;
      const unsigned short* g = hb + (size_t)grow * FEAT + kt * 32 + lk;
      unsigned short* l = &As[r * 32];  // wave-uniform base; lane i -> +i*16B
      __builtin_amdgcn_global_load_lds(
          (const __attribute__((address_space(1))) void*)g,
          (__attribute__((address_space(3))) void*)l, 16, 0, 0);
    }
    // Stage B: Bs[c][k], wave w covers cols [w*32, w*32+32)
#pragma unroll
    for (int p = 0; p < 2; ++p) {
      int r = w * 32 + p * 16;
      const unsigned short* g = Wt + (size_t)(c0 + r + lr) * FEAT + kt * 32 + lk;
      unsigned short* l = &Bs[r * 32];
      __builtin_amdgcn_global_load_lds(
          (const __attribute__((address_space(1))) void*)g,
          (__attribute__((address_space(3))) void*)l, 16, 0, 0);
    }
    __syncthreads();
    shortx8 af[4], bf[4];
#pragma unroll
    for (int mi = 0; mi < 4; ++mi)
      af[mi] = *(const shortx8*)&As[(wr * 64 + mi * 16 + mrow) * 32 + quad * 8];
#pragma unroll
    for (int ni = 0; ni < 4; ++ni)
      bf[ni] = *(const shortx8*)&Bs[(wc * 64 + ni * 16 + mrow) * 32 + quad * 8];
#pragma unroll
    for (int mi = 0; mi < 4; ++mi)
#pragma unroll
      for (int ni = 0; ni < 4; ++ni)
        acc[mi][ni] = __builtin_amdgcn_mfma_f32_16x16x32_bf16(
            af[mi], bf[ni], acc[mi][ni], 0, 0, 0);
    __syncthreads();
  }
  // Epilogue: C/D layout col=lane&15, row=quad*4+reg
#pragma unroll
  for (int mi = 0; mi < 4; ++mi) {
#pragma unroll
    for (int ni = 0; ni < 4; ++ni) {
      int col = c0 + wc * 64 + ni * 16 + mrow;
      float bias = bW[col];
#pragma unroll
      for (int r = 0; r < 4; ++r) {
        int row = row0 + wr * 64 + mi * 16 + quad * 4 + r;
        if (row < NNODES)
          Whb[(size_t)row * CDIM + col] = f2bf(acc[mi][ni][r] + bias);
      }
    }
  }
}

// Kernel 2: s12[n][0..7] = s1 per head; s12[n][8..15] = s2 + a_bias.
// One wave per node (4 waves/block). lane covers 4 cols.
__global__ __launch_bounds__(256) void calc_s12(
    const unsigned short* __restrict__ Whb, const float* __restrict__ a_src,
    const float* __restrict__ a_dst, const float* __restrict__ a_bias,
    float* __restrict__ s12) {
  int lane = threadIdx.x & 63;
  int node = blockIdx.x * 4 + (threadIdx.x >> 6);
  ushort4 vb = *(const ushort4*)&Whb[(size_t)node * CDIM + lane * 4];
  float4 a1 = ((const float4*)a_src)[lane];
  float4 a2 = ((const float4*)a_dst)[lane];
  float vx = bf2f(vb.x), vy = bf2f(vb.y), vz = bf2f(vb.z), vw = bf2f(vb.w);
  float acc1 = vx * a1.x + vy * a1.y + vz * a1.z + vw * a1.w;
  float acc2 = vx * a2.x + vy * a2.y + vz * a2.z + vw * a2.w;
#pragma unroll
  for (int off = 1; off < 8; off <<= 1) {
    acc1 += __shfl_xor(acc1, off, 64);
    acc2 += __shfl_xor(acc2, off, 64);
  }
  if ((lane & 7) == 0) {
    int hh = lane >> 3;
    s12[(size_t)node * 16 + hh] = acc1;
    s12[(size_t)node * 16 + 8 + hh] = acc2 + a_bias[hh];
  }
}

// Kernel 3: per-node softmax over its 16 contiguous incoming edges +
// weighted gather-sum of bf16 Whb[src] rows. Wave per node.
__global__ __launch_bounds__(256) void aggregate(
    const unsigned short* __restrict__ Whb, const float* __restrict__ s12,
    const int* __restrict__ src, float* __restrict__ out) {
  __shared__ int srcs_s[4][DEG];
  __shared__ float sc_s[4][DEG * NH];
  int wave = threadIdx.x >> 6, lane = threadIdx.x & 63;
  int n = blockIdx.x * 4 + wave;
  if (lane < DEG) srcs_s[wave][lane] = src[(size_t)n * DEG + lane];
  __syncthreads();
  int hh7 = lane & 7;
  float s2v = s12[(size_t)n * 16 + 8 + hh7];
#pragma unroll
  for (int p = 0; p < 2; ++p) {
    int i = lane + p * 64;
    int e = i >> 3;
    int s = srcs_s[wave][e];
    float sc = s12[(size_t)s * 16 + hh7] + s2v;
    sc_s[wave][i] = sc > 0.f ? sc : 0.2f * sc;  // leaky relu
  }
  __syncthreads();
  if (lane < 8) {
    float m = -1e30f;
#pragma unroll
    for (int e = 0; e < DEG; ++e) m = fmaxf(m, sc_s[wave][e * 8 + lane]);
    float sum = 0.f;
#pragma unroll
    for (int e = 0; e < DEG; ++e) {
      float ex = __expf(sc_s[wave][e * 8 + lane] - m);
      sc_s[wave][e * 8 + lane] = ex;
      sum += ex;
    }
    float inv = 1.f / sum;
#pragma unroll
    for (int e = 0; e < DEG; ++e) sc_s[wave][e * 8 + lane] *= inv;
  }
  __syncthreads();
  int hh = lane >> 3;  // lane covers cols [lane*4, lane*4+4) -> head lane/8
  float4 acc = make_float4(0.f, 0.f, 0.f, 0.f);
#pragma unroll
  for (int e = 0; e < DEG; ++e) {
    float wgt = sc_s[wave][e * 8 + hh];
    ushort4 v = *(const ushort4*)&Whb[(size_t)srcs_s[wave][e] * CDIM + lane * 4];
    acc.x += wgt * bf2f(v.x);
    acc.y += wgt * bf2f(v.y);
    acc.z += wgt * bf2f(v.z);
    acc.w += wgt * bf2f(v.w);
  }
  ((float4*)out)[(size_t)n * 64 + lane] = acc;
}

extern "C" void kernel_launch(void* const* d_in, const int* in_sizes, int n_in,
                              void* d_out, int out_size, void* d_ws, size_t ws_size,
                              hipStream_t stream) {
  const float* h = (const float*)d_in[0];
  const float* W = (const float*)d_in[1];
  const float* bW = (const float*)d_in[2];
  const float* a_src = (const float*)d_in[3];
  const float* a_dst = (const float*)d_in[4];
  const float* a_bias = (const float*)d_in[5];
  const int* src = (const int*)d_in[6];
  // d_in[7] (dst) unused: dst = repeat(arange(N), DEG) structurally.
  float* out = (float*)d_out;

  unsigned short* hb = (unsigned short*)d_ws;            // [N][256] bf16, 25.6 MB
  unsigned short* Whb = hb + (size_t)NNODES * FEAT;      // [N][256] bf16, 25.6 MB
  unsigned short* Wt = Whb + (size_t)NNODES * CDIM;      // [256][256] bf16, 131 KB
  float* s12 = (float*)(Wt + CDIM * FEAT);               // [N][16] fp32, 3.2 MB

  convert_inputs<<<12564, 256, 0, stream>>>(h, W, hb, Wt);
  dim3 g1((NNODES + 127) / 128, CDIM / 128);
  gemm_mfma<<<g1, 256, 0, stream>>>(hb, Wt, bW, Whb);
  calc_s12<<<NNODES / 4, 256, 0, stream>>>(Whb, a_src, a_dst, a_bias, s12);
  aggregate<<<NNODES / 4, 256, 0, stream>>>(Whb, s12, src, out);
}

// Round 3
// 198.558 us; speedup vs baseline: 1.6251x; 1.0932x over previous
//
#include <hip/hip_runtime.h>

#define NNODES 50000
#define FEAT 256
#define NH 8
#define DHEAD 32
#define DEG 16
#define CDIM 256  // NH*DHEAD

typedef __attribute__((ext_vector_type(4))) float floatx4;
typedef __attribute__((ext_vector_type(8))) short shortx8;

__device__ __forceinline__ unsigned short f2bf(float f) {
  union { float f; unsigned u; } v; v.f = f;
  unsigned r = v.u + 0x7fffu + ((v.u >> 16) & 1u);  // RN-even
  return (unsigned short)(r >> 16);
}
__device__ __forceinline__ float bf2f(unsigned short b) {
  union { unsigned u; float f; } v; v.u = ((unsigned)b) << 16;
  return v.f;
}

// Kernel 0: W [H][F][DH] fp32 -> Wt [c][k] bf16 (c = h*32+d, k = f).
// 64 blocks x 256 threads x 4 elems = 65536.
__global__ __launch_bounds__(256) void convert_wt(
    const float* __restrict__ W, unsigned short* __restrict__ Wt) {
  int t = blockIdx.x * 256 + threadIdx.x;
#pragma unroll
  for (int j = 0; j < 4; ++j) {
    int idx = t * 4 + j;  // [0, 65536)
    int c = idx >> 8, k = idx & 255;
    Wt[idx] = f2bf(W[(size_t)(c >> 5) * (FEAT * DHEAD) + (size_t)k * DHEAD + (c & 31)]);
  }
}

// Kernel 1 (fused): Whb[n][c] = bf16(sum_k h[n][k]*Wt[c][k] + bW[c]),
// plus s1[n][h] / s2[n][h] attention dots computed in the epilogue.
// Tile 64 rows x 256 cols (full C), BK=32, 256 threads = 4 waves; wave w
// owns cols [w*64, w*64+64) = heads {2w, 2w+1}. h is loaded fp32 ONCE,
// converted to bf16 in registers, ds_write'd to LDS.
__global__ __launch_bounds__(256) void gemm_fused(
    const float* __restrict__ h, const unsigned short* __restrict__ Wt,
    const float* __restrict__ bW, const float* __restrict__ a_src,
    const float* __restrict__ a_dst, unsigned short* __restrict__ Whb,
    float* __restrict__ s1g, float* __restrict__ s2g) {
  __shared__ unsigned short As[64 * 32];
  __shared__ unsigned short Bs[256 * 32];
  const int tid = threadIdx.x;
  const int w = tid >> 6, lane = tid & 63;
  const int row0 = blockIdx.x * 64;
  const int mrow = lane & 15, quad = lane >> 4;
  const int lr = lane >> 2, lk = (lane & 3) * 8;
  const int ar = tid >> 2, ak = (tid & 3) * 8;  // A staging: row, k-offset
  int agrow = row0 + ar;
  if (agrow > NNODES - 1) agrow = NNODES - 1;

  floatx4 acc[4][4] = {};

  for (int kt = 0; kt < FEAT / 32; ++kt) {
    // Stage A: 64x32 fp32 -> bf16 -> LDS (8 elems/thread, one b128 write)
    float4 v0 = *(const float4*)&h[(size_t)agrow * FEAT + kt * 32 + ak];
    float4 v1 = *(const float4*)&h[(size_t)agrow * FEAT + kt * 32 + ak + 4];
    shortx8 a8;
    a8[0] = (short)f2bf(v0.x); a8[1] = (short)f2bf(v0.y);
    a8[2] = (short)f2bf(v0.z); a8[3] = (short)f2bf(v0.w);
    a8[4] = (short)f2bf(v1.x); a8[5] = (short)f2bf(v1.y);
    a8[6] = (short)f2bf(v1.z); a8[7] = (short)f2bf(v1.w);
    *(shortx8*)&As[ar * 32 + ak] = a8;
    // Stage B: Bs[c][k], wave w covers c in [w*64, w*64+64), 4 issues
#pragma unroll
    for (int p = 0; p < 4; ++p) {
      int c = w * 64 + p * 16 + lr;
      const unsigned short* g = Wt + (size_t)c * FEAT + kt * 32 + lk;
      unsigned short* l = &Bs[(w * 64 + p * 16) * 32];
      __builtin_amdgcn_global_load_lds(
          (const __attribute__((address_space(1))) void*)g,
          (__attribute__((address_space(3))) void*)l, 16, 0, 0);
    }
    __syncthreads();
    shortx8 af[4], bfr[4];
#pragma unroll
    for (int mi = 0; mi < 4; ++mi)
      af[mi] = *(const shortx8*)&As[(mi * 16 + mrow) * 32 + quad * 8];
#pragma unroll
    for (int ni = 0; ni < 4; ++ni)
      bfr[ni] = *(const shortx8*)&Bs[(w * 64 + ni * 16 + mrow) * 32 + quad * 8];
#pragma unroll
    for (int mi = 0; mi < 4; ++mi)
#pragma unroll
      for (int ni = 0; ni < 4; ++ni)
        acc[mi][ni] = __builtin_amdgcn_mfma_f32_16x16x32_bf16(
            af[mi], bfr[ni], acc[mi][ni], 0, 0, 0);
    __syncthreads();
  }

  // Epilogue: bias + bf16 store + fused s1/s2 (per-head dots).
  // Wave w cols: col = w*64 + ni*16 + mrow; heads h0 = 2w (ni 0,1), h1 = 2w+1.
  float aw_s[4], aw_d[4], bias[4];
#pragma unroll
  for (int ni = 0; ni < 4; ++ni) {
    int col = w * 64 + ni * 16 + mrow;
    aw_s[ni] = a_src[col];  // flat [H*DH] == col
    aw_d[ni] = a_dst[col];
    bias[ni] = bW[col];
  }
#pragma unroll
  for (int mi = 0; mi < 4; ++mi) {
#pragma unroll
    for (int ni = 0; ni < 4; ++ni) {
      int col = w * 64 + ni * 16 + mrow;
#pragma unroll
      for (int r = 0; r < 4; ++r) {
        int row = row0 + mi * 16 + quad * 4 + r;
        float val = acc[mi][ni][r] + bias[ni];
        acc[mi][ni][r] = val;  // keep fp32 for s1/s2
        if (row < NNODES) Whb[(size_t)row * CDIM + col] = f2bf(val);
      }
    }
#pragma unroll
    for (int r = 0; r < 4; ++r) {
      float s1h0 = acc[mi][0][r] * aw_s[0] + acc[mi][1][r] * aw_s[1];
      float s1h1 = acc[mi][2][r] * aw_s[2] + acc[mi][3][r] * aw_s[3];
      float s2h0 = acc[mi][0][r] * aw_d[0] + acc[mi][1][r] * aw_d[1];
      float s2h1 = acc[mi][2][r] * aw_d[2] + acc[mi][3][r] * aw_d[3];
#pragma unroll
      for (int off = 1; off < 16; off <<= 1) {
        s1h0 += __shfl_xor(s1h0, off, 64);
        s1h1 += __shfl_xor(s1h1, off, 64);
        s2h0 += __shfl_xor(s2h0, off, 64);
        s2h1 += __shfl_xor(s2h1, off, 64);
      }
      if (mrow == 0) {
        int row = row0 + mi * 16 + quad * 4 + r;
        if (row < NNODES) {
          float2 s1v; s1v.x = s1h0; s1v.y = s1h1;
          float2 s2v; s2v.x = s2h0; s2v.y = s2h1;
          *(float2*)&s1g[(size_t)row * NH + w * 2] = s1v;
          *(float2*)&s2g[(size_t)row * NH + w * 2] = s2v;
        }
      }
    }
  }
}

// Kernel 2: per-node softmax over its 16 contiguous incoming edges +
// weighted gather-sum of bf16 Whb[src] rows. Wave per node.
__global__ __launch_bounds__(256) void aggregate(
    const unsigned short* __restrict__ Whb, const float* __restrict__ s1g,
    const float* __restrict__ s2g, const float* __restrict__ a_bias,
    const int* __restrict__ src, float* __restrict__ out) {
  __shared__ int srcs_s[4][DEG];
  __shared__ float sc_s[4][DEG * NH];
  int wave = threadIdx.x >> 6, lane = threadIdx.x & 63;
  int n = blockIdx.x * 4 + wave;
  if (lane < DEG) srcs_s[wave][lane] = src[(size_t)n * DEG + lane];
  __syncthreads();
  int hh7 = lane & 7;
  float s2v = s2g[(size_t)n * NH + hh7] + a_bias[hh7];
#pragma unroll
  for (int p = 0; p < 2; ++p) {
    int i = lane + p * 64;
    int e = i >> 3;
    int s = srcs_s[wave][e];
    float sc = s1g[(size_t)s * NH + hh7] + s2v;
    sc_s[wave][i] = sc > 0.f ? sc : 0.2f * sc;  // leaky relu
  }
  __syncthreads();
  if (lane < 8) {
    float m = -1e30f;
#pragma unroll
    for (int e = 0; e < DEG; ++e) m = fmaxf(m, sc_s[wave][e * 8 + lane]);
    float sum = 0.f;
#pragma unroll
    for (int e = 0; e < DEG; ++e) {
      float ex = __expf(sc_s[wave][e * 8 + lane] - m);
      sc_s[wave][e * 8 + lane] = ex;
      sum += ex;
    }
    float inv = 1.f / sum;
#pragma unroll
    for (int e = 0; e < DEG; ++e) sc_s[wave][e * 8 + lane] *= inv;
  }
  __syncthreads();
  int hh = lane >> 3;  // lane covers cols [lane*4, lane*4+4) -> head lane/8
  float4 acc = make_float4(0.f, 0.f, 0.f, 0.f);
#pragma unroll
  for (int e = 0; e < DEG; ++e) {
    float wgt = sc_s[wave][e * 8 + hh];
    ushort4 v = *(const ushort4*)&Whb[(size_t)srcs_s[wave][e] * CDIM + lane * 4];
    acc.x += wgt * bf2f(v.x);
    acc.y += wgt * bf2f(v.y);
    acc.z += wgt * bf2f(v.z);
    acc.w += wgt * bf2f(v.w);
  }
  ((float4*)out)[(size_t)n * 64 + lane] = acc;
}

extern "C" void kernel_launch(void* const* d_in, const int* in_sizes, int n_in,
                              void* d_out, int out_size, void* d_ws, size_t ws_size,
                              hipStream_t stream) {
  const float* h = (const float*)d_in[0];
  const float* W = (const float*)d_in[1];
  const float* bW = (const float*)d_in[2];
  const float* a_src = (const float*)d_in[3];
  const float* a_dst = (const float*)d_in[4];
  const float* a_bias = (const float*)d_in[5];
  const int* src = (const int*)d_in[6];
  // d_in[7] (dst) unused: dst = repeat(arange(N), DEG) structurally.
  float* out = (float*)d_out;

  unsigned short* Whb = (unsigned short*)d_ws;          // [N][256] bf16, 25.6 MB
  unsigned short* Wt = Whb + (size_t)NNODES * CDIM;     // [256][256] bf16, 131 KB
  float* s1g = (float*)(Wt + CDIM * FEAT);              // [N][8] fp32, 1.6 MB
  float* s2g = s1g + (size_t)NNODES * NH;               // [N][8] fp32, 1.6 MB

  convert_wt<<<64, 256, 0, stream>>>(W, Wt);
  gemm_fused<<<(NNODES + 63) / 64, 256, 0, stream>>>(h, Wt, bW, a_src, a_dst,
                                                     Whb, s1g, s2g);
  aggregate<<<NNODES / 4, 256, 0, stream>>>(Whb, s1g, s2g, a_bias, src, out);
}